// Round 3
// baseline (562.592 us; speedup 1.0000x reference)
//
#include <hip/hip_runtime.h>
#include <cmath>

// out = (log(|DCT2(x)| + 1e-13) - mean) / std,  x: [384][256][256] f32.
// R1/R2 evidence: np reference accumulates in FLOAT32 (both fp64 variants
// fail at ~0.4 absmax via log() of noise-dominated near-zero coefficients).
// To match its noise we replicate np.einsum's BLAS path exactly:
//   stage 1: T1 = CH @ X    (f32 FMA chain over i = 0..255 ascending)
//   round T1 to f32 (materialized intermediate)
//   stage 2: Y  = T1 @ CW^T (f32 FMA chain over j = 0..255 ascending)
// Basis: cos/scale in f64, cast to f32 (matches jnp.asarray(..., float32)).
// K=256 < BLAS KC => micro-kernels use a single sequential FMA accumulator
// per element, which fmaf chains reproduce bit-exactly.

#define HN    256
#define NIMG  384
#define SLAB  32    // k1 rows per block -> 8 blocks per image

// ---- f32 basis table: Tdf[i][k] = (float)( cos(pi*(2i+1)*k/512) * s(k) ) --
__global__ void basis_init(float* __restrict__ Tdf) {
    int idx = blockIdx.x * 256 + threadIdx.x;   // 65536
    int i = idx >> 8, k = idx & 255;
    double c = cos(M_PI * (2.0 * i + 1.0) * (double)k / 512.0);
    double s = (k == 0) ? sqrt(1.0 / 256.0) : sqrt(2.0 / 256.0);
    Tdf[idx] = (float)(c * s);
}

__global__ __launch_bounds__(256, 3) void dct2_f32(
    const float* __restrict__ X,
    const float* __restrict__ Tdf,
    const float* __restrict__ meanp,
    const float* __restrict__ stdp,
    float*       __restrict__ out)
{
    __shared__ union SU {
        struct {
            float Xs[8][HN];      // X i-chunk, 8 rows            (8 KB)
            float CHc[8][SLAB];   // CH chunk: Tdf[i0+ii][k0+kl]  (1 KB)
        } p1;
        float Bc[16][HN];         // phase-2 CW chunk             (16 KB)
    } u;
    __shared__ float T1s[SLAB][HN + 1];  // odd stride 257: bank=(row+col)%32

    const int t   = threadIdx.x;
    const int img = blockIdx.x >> 3;
    const int k0  = (blockIdx.x & 7) * SLAB;
    const float* __restrict__ Xi = X + (size_t)img * (HN * HN);

    const int ci = t & 7;    // kl = 4*ci + r, r=0..3
    const int ib = t >> 3;   // j/k2 group: 8*ib + q, q=0..7  (ib=0..31)

    // -------- Phase 1: T1[kl][j] = sum_i CH[k0+kl, i] * X[i][j] ------------
    // CH[k,i] = Tdf[i][k]. Chain over i strictly ascending (i0 asc, ii asc).
    float acc[8][4];
    #pragma unroll
    for (int q = 0; q < 8; ++q)
        #pragma unroll
        for (int r = 0; r < 4; ++r) acc[q][r] = 0.0f;

    for (int i0 = 0; i0 < HN; i0 += 8) {
        {   // stage X rows i0..i0+7 (coalesced float4) + 8x32 CH chunk
            int rr = t >> 5, cc = (t & 31) * 4;
            float4 a = *(const float4*)(Xi + (i0 + rr) * HN + cc);
            float4 b = *(const float4*)(Xi + (i0 + rr) * HN + cc + 128);
            *(float4*)&u.p1.Xs[rr][cc]       = a;
            *(float4*)&u.p1.Xs[rr][cc + 128] = b;
            u.p1.CHc[rr][t & 31] = Tdf[(i0 + rr) * HN + k0 + (t & 31)];
        }
        __syncthreads();
        #pragma unroll
        for (int ii = 0; ii < 8; ++ii) {
            float xr[8];
            *(float4*)&xr[0] = *(const float4*)&u.p1.Xs[ii][8 * ib];     // bcast
            *(float4*)&xr[4] = *(const float4*)&u.p1.Xs[ii][8 * ib + 4];
            float ch[4];
            *(float4*)&ch[0] = *(const float4*)&u.p1.CHc[ii][4 * ci];
            #pragma unroll
            for (int q = 0; q < 8; ++q)
                #pragma unroll
                for (int r = 0; r < 4; ++r)
                    acc[q][r] = fmaf(ch[r], xr[q], acc[q][r]);
        }
        __syncthreads();
    }
    #pragma unroll
    for (int q = 0; q < 8; ++q)
        #pragma unroll
        for (int r = 0; r < 4; ++r)
            T1s[4 * ci + r][8 * ib + q] = acc[q][r];   // f32 round (np interm.)
    __syncthreads();

    // -------- Phase 2: Y[kl][k2] = sum_j T1[kl][j] * Tdf[j][k2] ------------
    // Chain over j strictly ascending (j0 asc, p asc).
    float acc2[8][4];
    #pragma unroll
    for (int q = 0; q < 8; ++q)
        #pragma unroll
        for (int r = 0; r < 4; ++r) acc2[q][r] = 0.0f;

    for (int j0 = 0; j0 < HN; j0 += 16) {
        #pragma unroll
        for (int rep = 0; rep < 4; ++rep) {   // stage Bc[p][k2]=Tdf[j0+p][k2]
            int idx = rep * 1024 + t * 4;
            int p = idx >> 8, c = idx & 255;
            *(float4*)&u.Bc[p][c] = *(const float4*)(Tdf + (j0 + p) * HN + c);
        }
        __syncthreads();
        #pragma unroll
        for (int p = 0; p < 16; ++p) {
            float a[4];
            #pragma unroll
            for (int r = 0; r < 4; ++r) a[r] = T1s[4 * ci + r][j0 + p];
            float b[8];
            *(float4*)&b[0] = *(const float4*)&u.Bc[p][8 * ib];
            *(float4*)&b[4] = *(const float4*)&u.Bc[p][8 * ib + 4];
            #pragma unroll
            for (int q = 0; q < 8; ++q)
                #pragma unroll
                for (int r = 0; r < 4; ++r)
                    acc2[q][r] = fmaf(a[r], b[q], acc2[q][r]);
        }
        __syncthreads();
    }

    // -------- Epilogue: log/normalize; LDS transpose for coalesced store ---
    const float mean = meanp[0];
    const float stdv = stdp[0];
    #pragma unroll
    for (int q = 0; q < 8; ++q)
        #pragma unroll
        for (int r = 0; r < 4; ++r) {
            float v = (logf(fabsf(acc2[q][r]) + 1e-13f) - mean) / stdv;
            T1s[4 * ci + r][8 * ib + q] = v;   // T1s free after last chunk
        }
    __syncthreads();

    float* __restrict__ O = out + (size_t)img * (HN * HN) + (size_t)k0 * HN;
    #pragma unroll
    for (int rep = 0; rep < 8; ++rep) {
        int idx = rep * 1024 + t * 4;
        int row = idx >> 8, col = idx & 255;
        float4 v = make_float4(T1s[row][col], T1s[row][col + 1],
                               T1s[row][col + 2], T1s[row][col + 3]);
        *(float4*)(O + row * HN + col) = v;
    }
}

extern "C" void kernel_launch(void* const* d_in, const int* in_sizes, int n_in,
                              void* d_out, int out_size, void* d_ws, size_t ws_size,
                              hipStream_t stream) {
    const float* X     = (const float*)d_in[0];
    const float* meanp = (const float*)d_in[1];
    const float* stdp  = (const float*)d_in[2];
    float* Tdf = (float*)d_ws;            // 256 KB f32 basis table

    basis_init<<<256, 256, 0, stream>>>(Tdf);
    dct2_f32<<<NIMG * (HN / SLAB), 256, 0, stream>>>(
        X, Tdf, meanp, stdp, (float*)d_out);
}

// Round 4
// 448.931 us; speedup vs baseline: 1.2532x; 1.2532x over previous
//
#include <hip/hip_runtime.h>
#include <cmath>

// out = (log(|DCT2(x)| + 1e-13) - mean) / std,  x: [384][256][256] f32.
// CORRECTNESS CONTRACT (R1-R3 evidence): the np reference accumulates in f32;
// near-zero DCT coefficients are f32 rounding NOISE and log() demands we
// reproduce that noise ~exactly. Therefore every output element must be a
// single sequential fmaf chain, i ascending (stage 1) / j ascending (stage 2),
// with the stage-1 result rounded to f32. NO MFMA, NO split accumulators.
//
// R3 passed at 499us but VALUBusy=51%, occupancy=33% (49.7KB LDS, 96 barriers,
// X re-staged 8x). R4: two-kernel split through a f32 T1 workspace (bit-equal
// to the materialized np intermediate): each kernel ~10KB LDS, 64 FMA per
// ~5 LDS reads, X/T1 read once. Fallback to the proven fused kernel if
// ws_size can't hold the 100.7MB intermediate.

#define HN    256
#define NIMG  384

// ---- f32 basis: Tdf[i][k] = (float)( cos(pi*(2i+1)*k/512) * s(k) ) --------
__global__ void basis_init(float* __restrict__ Tdf) {
    int idx = blockIdx.x * 256 + threadIdx.x;   // 65536
    int i = idx >> 8, k = idx & 255;
    double c = cos(M_PI * (2.0 * i + 1.0) * (double)k / 512.0);
    double s = (k == 0) ? sqrt(1.0 / 256.0) : sqrt(2.0 / 256.0);
    Tdf[idx] = (float)(c * s);
}

// ======================= two-kernel path ===================================
// Kernel A: T1[img][k1][j] = sum_i Tdf[i][k1] * X[img][i][j]   (i ascending)
// Block: one image x 64-wide j-slab; thread owns 16 k1 x 4 j = 64 accs.
__global__ __launch_bounds__(256, 4) void t1_kernel(
    const float* __restrict__ X, const float* __restrict__ Tdf,
    float* __restrict__ T1)
{
    __shared__ float Xs[8][64];     // X i-chunk, j-slab        (2 KB)
    __shared__ float CHs[8][HN];    // basis rows i0..i0+7      (8 KB)

    const int t   = threadIdx.x;
    const int img = blockIdx.x >> 2;
    const int js  = (blockIdx.x & 3) * 64;
    const float* __restrict__ Xi = X + (size_t)img * (HN * HN);

    const int ci = t & 15;   // j  = js + 4*ci + jr
    const int ib = t >> 4;   // k1 = 64*s + 4*ib + r

    float acc[4][4][4];      // [s][r][jr]
    #pragma unroll
    for (int s = 0; s < 4; ++s)
        #pragma unroll
        for (int r = 0; r < 4; ++r)
            #pragma unroll
            for (int jr = 0; jr < 4; ++jr) acc[s][r][jr] = 0.0f;

    for (int i0 = 0; i0 < HN; i0 += 8) {
        {   // stage: Xs 512 floats (float2/lane), CHs 2048 floats (2x b128,
            // lane-consecutive 16B chunks -> conflict-free, coalesced)
            int rr = t >> 5, cc = (t & 31) * 2;
            float2 v = *(const float2*)(Xi + (i0 + rr) * HN + js + cc);
            Xs[rr][cc] = v.x; Xs[rr][cc + 1] = v.y;
            #pragma unroll
            for (int rep = 0; rep < 2; ++rep) {
                int idx = rep * 1024 + t * 4;
                int row = idx >> 8, col = idx & 255;
                *(float4*)&CHs[row][col] =
                    *(const float4*)(Tdf + (i0 + row) * HN + col);
            }
        }
        __syncthreads();
        #pragma unroll
        for (int ii = 0; ii < 8; ++ii) {
            float xv[4];
            *(float4*)xv = *(const float4*)&Xs[ii][4 * ci];
            float ch[4][4];
            #pragma unroll
            for (int s = 0; s < 4; ++s)
                *(float4*)ch[s] = *(const float4*)&CHs[ii][64 * s + 4 * ib];
            #pragma unroll
            for (int s = 0; s < 4; ++s)
                #pragma unroll
                for (int r = 0; r < 4; ++r)
                    #pragma unroll
                    for (int jr = 0; jr < 4; ++jr)
                        acc[s][r][jr] = fmaf(ch[s][r], xv[jr], acc[s][r][jr]);
        }
        __syncthreads();
    }

    float* __restrict__ T1i = T1 + (size_t)img * (HN * HN);
    #pragma unroll
    for (int s = 0; s < 4; ++s)
        #pragma unroll
        for (int r = 0; r < 4; ++r)
            *(float4*)(T1i + (64 * s + 4 * ib + r) * HN + js + 4 * ci) =
                *(const float4*)acc[s][r];   // f32 intermediate (np-equal)
}

// Kernel B: Y[k1][k2] = sum_j T1[k1][j] * Tdf[j][k2]   (j ascending) + epilogue
// Block: one image x 64-wide k1-slab; thread owns 4 k1 x 16 k2 = 64 accs.
__global__ __launch_bounds__(256, 4) void y_kernel(
    const float* __restrict__ T1, const float* __restrict__ Tdf,
    const float* __restrict__ meanp, const float* __restrict__ stdp,
    float* __restrict__ out)
{
    __shared__ float T1c[64][9];    // T1 k1-slab x 8-j chunk   (2.25 KB)
    __shared__ float Bc[8][HN];     // basis rows j0..j0+7      (8 KB)

    const int t   = threadIdx.x;
    const int img = blockIdx.x >> 2;
    const int ks  = (blockIdx.x & 3) * 64;
    const float* __restrict__ T1i = T1 + (size_t)img * (HN * HN);

    const int ci = t & 15;   // k2 = 64*s + 4*ci + c
    const int ib = t >> 4;   // k1 = ks + 4*ib + r

    float acc[4][4][4];      // [s][r][c]
    #pragma unroll
    for (int s = 0; s < 4; ++s)
        #pragma unroll
        for (int r = 0; r < 4; ++r)
            #pragma unroll
            for (int c = 0; c < 4; ++c) acc[s][r][c] = 0.0f;

    for (int j0 = 0; j0 < HN; j0 += 8) {
        {   // stage: T1c 512 floats (float2/lane), Bc 2048 floats (2x b128)
            int rr = t >> 2, cc = (t & 3) * 2;
            float2 v = *(const float2*)(T1i + (ks + rr) * HN + j0 + cc);
            T1c[rr][cc] = v.x; T1c[rr][cc + 1] = v.y;
            #pragma unroll
            for (int rep = 0; rep < 2; ++rep) {
                int idx = rep * 1024 + t * 4;
                int row = idx >> 8, col = idx & 255;
                *(float4*)&Bc[row][col] =
                    *(const float4*)(Tdf + (j0 + row) * HN + col);
            }
        }
        __syncthreads();
        #pragma unroll
        for (int p = 0; p < 8; ++p) {
            float a[4];
            #pragma unroll
            for (int r = 0; r < 4; ++r) a[r] = T1c[4 * ib + r][p];
            float b[4][4];
            #pragma unroll
            for (int s = 0; s < 4; ++s)
                *(float4*)b[s] = *(const float4*)&Bc[p][64 * s + 4 * ci];
            #pragma unroll
            for (int s = 0; s < 4; ++s)
                #pragma unroll
                for (int r = 0; r < 4; ++r)
                    #pragma unroll
                    for (int c = 0; c < 4; ++c)
                        acc[s][r][c] = fmaf(a[r], b[s][c], acc[s][r][c]);
        }
        __syncthreads();
    }

    const float mean = meanp[0];
    const float stdv = stdp[0];
    float* __restrict__ O = out + (size_t)img * (HN * HN);
    #pragma unroll
    for (int s = 0; s < 4; ++s)
        #pragma unroll
        for (int r = 0; r < 4; ++r) {
            float4 v;
            v.x = (logf(fabsf(acc[s][r][0]) + 1e-13f) - mean) / stdv;
            v.y = (logf(fabsf(acc[s][r][1]) + 1e-13f) - mean) / stdv;
            v.z = (logf(fabsf(acc[s][r][2]) + 1e-13f) - mean) / stdv;
            v.w = (logf(fabsf(acc[s][r][3]) + 1e-13f) - mean) / stdv;
            *(float4*)(O + (ks + 4 * ib + r) * HN + 64 * s + 4 * ci) = v;
        }
}

// ======================= fused fallback (R3, proven) =======================
#define SLAB 32
__global__ __launch_bounds__(256, 3) void dct2_f32(
    const float* __restrict__ X, const float* __restrict__ Tdf,
    const float* __restrict__ meanp, const float* __restrict__ stdp,
    float* __restrict__ out)
{
    __shared__ union SU {
        struct { float Xs[8][HN]; float CHc[8][SLAB]; } p1;
        float Bc[16][HN];
    } u;
    __shared__ float T1s[SLAB][HN + 1];

    const int t   = threadIdx.x;
    const int img = blockIdx.x >> 3;
    const int k0  = (blockIdx.x & 7) * SLAB;
    const float* __restrict__ Xi = X + (size_t)img * (HN * HN);
    const int ci = t & 7;
    const int ib = t >> 3;

    float acc[8][4];
    #pragma unroll
    for (int q = 0; q < 8; ++q)
        #pragma unroll
        for (int r = 0; r < 4; ++r) acc[q][r] = 0.0f;

    for (int i0 = 0; i0 < HN; i0 += 8) {
        {
            int rr = t >> 5, cc = (t & 31) * 4;
            float4 a = *(const float4*)(Xi + (i0 + rr) * HN + cc);
            float4 b = *(const float4*)(Xi + (i0 + rr) * HN + cc + 128);
            *(float4*)&u.p1.Xs[rr][cc]       = a;
            *(float4*)&u.p1.Xs[rr][cc + 128] = b;
            u.p1.CHc[rr][t & 31] = Tdf[(i0 + rr) * HN + k0 + (t & 31)];
        }
        __syncthreads();
        #pragma unroll
        for (int ii = 0; ii < 8; ++ii) {
            float xr[8];
            *(float4*)&xr[0] = *(const float4*)&u.p1.Xs[ii][8 * ib];
            *(float4*)&xr[4] = *(const float4*)&u.p1.Xs[ii][8 * ib + 4];
            float ch[4];
            *(float4*)&ch[0] = *(const float4*)&u.p1.CHc[ii][4 * ci];
            #pragma unroll
            for (int q = 0; q < 8; ++q)
                #pragma unroll
                for (int r = 0; r < 4; ++r)
                    acc[q][r] = fmaf(ch[r], xr[q], acc[q][r]);
        }
        __syncthreads();
    }
    #pragma unroll
    for (int q = 0; q < 8; ++q)
        #pragma unroll
        for (int r = 0; r < 4; ++r)
            T1s[4 * ci + r][8 * ib + q] = acc[q][r];
    __syncthreads();

    float acc2[8][4];
    #pragma unroll
    for (int q = 0; q < 8; ++q)
        #pragma unroll
        for (int r = 0; r < 4; ++r) acc2[q][r] = 0.0f;

    for (int j0 = 0; j0 < HN; j0 += 16) {
        #pragma unroll
        for (int rep = 0; rep < 4; ++rep) {
            int idx = rep * 1024 + t * 4;
            int p = idx >> 8, c = idx & 255;
            *(float4*)&u.Bc[p][c] = *(const float4*)(Tdf + (j0 + p) * HN + c);
        }
        __syncthreads();
        #pragma unroll
        for (int p = 0; p < 16; ++p) {
            float a[4];
            #pragma unroll
            for (int r = 0; r < 4; ++r) a[r] = T1s[4 * ci + r][j0 + p];
            float b[8];
            *(float4*)&b[0] = *(const float4*)&u.Bc[p][8 * ib];
            *(float4*)&b[4] = *(const float4*)&u.Bc[p][8 * ib + 4];
            #pragma unroll
            for (int q = 0; q < 8; ++q)
                #pragma unroll
                for (int r = 0; r < 4; ++r)
                    acc2[q][r] = fmaf(a[r], b[q], acc2[q][r]);
        }
        __syncthreads();
    }

    const float mean = meanp[0];
    const float stdv = stdp[0];
    #pragma unroll
    for (int q = 0; q < 8; ++q)
        #pragma unroll
        for (int r = 0; r < 4; ++r) {
            float v = (logf(fabsf(acc2[q][r]) + 1e-13f) - mean) / stdv;
            T1s[4 * ci + r][8 * ib + q] = v;
        }
    __syncthreads();

    float* __restrict__ O = out + (size_t)img * (HN * HN) + (size_t)k0 * HN;
    #pragma unroll
    for (int rep = 0; rep < 8; ++rep) {
        int idx = rep * 1024 + t * 4;
        int row = idx >> 8, col = idx & 255;
        float4 v = make_float4(T1s[row][col], T1s[row][col + 1],
                               T1s[row][col + 2], T1s[row][col + 3]);
        *(float4*)(O + row * HN + col) = v;
    }
}

extern "C" void kernel_launch(void* const* d_in, const int* in_sizes, int n_in,
                              void* d_out, int out_size, void* d_ws, size_t ws_size,
                              hipStream_t stream) {
    const float* X     = (const float*)d_in[0];
    const float* meanp = (const float*)d_in[1];
    const float* stdp  = (const float*)d_in[2];

    float* Tdf = (float*)d_ws;                       // 256 KB basis
    const size_t T1_OFF    = 256 * 1024;
    const size_t T1_BYTES  = (size_t)NIMG * HN * HN * sizeof(float);  // 100.7MB

    basis_init<<<256, 256, 0, stream>>>(Tdf);

    if (ws_size >= T1_OFF + T1_BYTES) {
        float* T1 = (float*)((char*)d_ws + T1_OFF);
        t1_kernel<<<NIMG * 4, 256, 0, stream>>>(X, Tdf, T1);
        y_kernel <<<NIMG * 4, 256, 0, stream>>>(T1, Tdf, meanp, stdp,
                                                (float*)d_out);
    } else {
        dct2_f32<<<NIMG * 8, 256, 0, stream>>>(X, Tdf, meanp, stdp,
                                               (float*)d_out);
    }
}